// Round 1
// 406.235 us; speedup vs baseline: 1.0062x; 1.0062x over previous
//
#include <hip/hip_runtime.h>
#include <cstdint>

typedef __bf16 bf16_t;
typedef __bf16 bf16x4 __attribute__((ext_vector_type(4)));
typedef __bf16 bf16x8 __attribute__((ext_vector_type(8)));
typedef float f32x4 __attribute__((ext_vector_type(4)));

#define B_ 4
#define S_ 1024
#define D_ 1024
#define HID_ 4096
#define MEG (1u << 20)

// ---------------- workspace layout (bytes) ----------------
static const size_t OFF_WBF  = 0;                 // 12M bf16 (Wq,Wk,Wv,Wo,W1,W2)
static const size_t OFF_BQKV = 25165824;          // 3072 f32
static const size_t OFF_MOD  = 25178112;          // 4*6144 f32
static const size_t OFF_H    = 25276416;          // 4096*1024 bf16
static const size_t OFF_QKV  = 33665024;          // 4096*3072 bf16
static const size_t OFF_VT   = 58830848;          // 4*16*64*1024 bf16
static const size_t OFF_ATTN = 67219456;          // 4096*1024 bf16
static const size_t OFF_X1   = 75608064;          // 4096*1024 f32
static const size_t OFF_PART = 92385280;          // 2 * 4096*1024 f32 (split-K partials)
static const size_t OFF_MLPH = 159494144;         // 4096*4096 bf16 = 32MB

// ---------------- async global->LDS (16B/lane) ----------------
__device__ __forceinline__ void async_copy16(const bf16_t* g, bf16_t* l) {
  __builtin_amdgcn_global_load_lds(
      (__attribute__((address_space(1))) void*)(g),
      (__attribute__((address_space(3))) void*)(l), 16, 0, 0);
}

// ---------------- weight convert + bias pack ----------------
__global__ __launch_bounds__(256) void convert_pack(
    const float* __restrict__ Wq, const float* __restrict__ Wk,
    const float* __restrict__ Wv, const float* __restrict__ Wo,
    const float* __restrict__ W1, const float* __restrict__ W2,
    const float* __restrict__ bq, const float* __restrict__ bk,
    const float* __restrict__ bv, bf16_t* __restrict__ wbf,
    float* __restrict__ bqkv) {
  const int y = blockIdx.y;
  if (y == 6) {
    int i = blockIdx.x * 256 + threadIdx.x;
    if (i < 3072)
      bqkv[i] = i < 1024 ? bq[i] : (i < 2048 ? bk[i - 1024] : bv[i - 2048]);
    return;
  }
  const float* src; bf16_t* dst; int n;
  switch (y) {
    case 0: src = Wq; dst = wbf;           n = MEG;     break;
    case 1: src = Wk; dst = wbf + MEG;     n = MEG;     break;
    case 2: src = Wv; dst = wbf + 2*MEG;   n = MEG;     break;
    case 3: src = Wo; dst = wbf + 3*MEG;   n = MEG;     break;
    case 4: src = W1; dst = wbf + 4*MEG;   n = 4*MEG;   break;
    default: src = W2; dst = wbf + 8*MEG;  n = 4*MEG;   break;
  }
  int idx = (blockIdx.x * 256 + threadIdx.x) * 4;
  if (idx < n) {
    float4 v = *(const float4*)(src + idx);
    bf16x4 pk;
    pk.x = (__bf16)v.x; pk.y = (__bf16)v.y; pk.z = (__bf16)v.z; pk.w = (__bf16)v.w;
    *(bf16x4*)(dst + idx) = pk;
  }
}

// ---------------- adaLN: one wave per output o, all 4 batches ----------------
__global__ __launch_bounds__(256) void ada_mod(
    const float* __restrict__ cond, const float* __restrict__ Wada,
    const float* __restrict__ bada, float* __restrict__ mod) {
  const int wave = threadIdx.x >> 6, lane = threadIdx.x & 63;
  const int o = blockIdx.x * 4 + wave;      // 0..6143
  const float* wr = Wada + (size_t)o * D_;
  float a0 = 0.f, a1 = 0.f, a2 = 0.f, a3 = 0.f;
#pragma unroll
  for (int l = 0; l < 16; l++) {
    int i = l * 64 + lane;
    float w = wr[i];
    float c0 = cond[i], c1 = cond[1024 + i], c2 = cond[2048 + i], c3 = cond[3072 + i];
    a0 += w * (c0 / (1.0f + __expf(-c0)));
    a1 += w * (c1 / (1.0f + __expf(-c1)));
    a2 += w * (c2 / (1.0f + __expf(-c2)));
    a3 += w * (c3 / (1.0f + __expf(-c3)));
  }
#pragma unroll
  for (int offs = 32; offs; offs >>= 1) {
    a0 += __shfl_xor(a0, offs);
    a1 += __shfl_xor(a1, offs);
    a2 += __shfl_xor(a2, offs);
    a3 += __shfl_xor(a3, offs);
  }
  if (lane == 0) {
    float bb = bada[o];
    mod[o]          = a0 + bb;
    mod[6144 + o]   = a1 + bb;
    mod[12288 + o]  = a2 + bb;
    mod[18432 + o]  = a3 + bb;
  }
}

// ---------------- LayerNorm + modulate -> bf16 ----------------
__global__ __launch_bounds__(256) void ln_modulate(
    const float* __restrict__ X, const float* __restrict__ mod,
    bf16_t* __restrict__ H, int goff) {
  const int row = blockIdx.x;
  const int b = row >> 10;
  const int t = threadIdx.x;
  const float* xr = X + (size_t)row * D_;
  float4 xv = *(const float4*)(xr + t * 4);
  float s = xv.x + xv.y + xv.z + xv.w;
  float q = xv.x*xv.x + xv.y*xv.y + xv.z*xv.z + xv.w*xv.w;
  const int wave = t >> 6, lane = t & 63;
#pragma unroll
  for (int offs = 32; offs; offs >>= 1) {
    s += __shfl_down(s, offs);
    q += __shfl_down(q, offs);
  }
  __shared__ float sb[4][2];
  if (lane == 0) { sb[wave][0] = s; sb[wave][1] = q; }
  __syncthreads();
  float st = sb[0][0] + sb[1][0] + sb[2][0] + sb[3][0];
  float qt = sb[0][1] + sb[1][1] + sb[2][1] + sb[3][1];
  float mu = st * (1.0f / D_);
  float var = qt * (1.0f / D_) - mu * mu;
  float rstd = rsqrtf(var + 1e-6f);
  const float* mb = mod + (size_t)b * 6144 + goff;
  const int c = t * 4;
  float4 gm = *(const float4*)(mb + c);
  float4 bt = *(const float4*)(mb + 1024 + c);
  bf16x4 pk;
  pk.x = (__bf16)((xv.x - mu) * rstd * (1.0f + bt.x) + gm.x);
  pk.y = (__bf16)((xv.y - mu) * rstd * (1.0f + bt.y) + gm.y);
  pk.z = (__bf16)((xv.z - mu) * rstd * (1.0f + bt.z) + gm.z);
  pk.w = (__bf16)((xv.w - mu) * rstd * (1.0f + bt.w) + gm.w);
  *(bf16x4*)(H + (size_t)row * D_ + c) = pk;
}

// ---------------- V transpose: vT[b,h,d,s] <- qkv[b,s, 2048+h*64+d] ----------------
__global__ __launch_bounds__(256) void transpose_v(
    const bf16_t* __restrict__ qkv, bf16_t* __restrict__ vT) {
  __shared__ bf16_t tile[64][65];
  const int bh = blockIdx.y;
  const int b = bh >> 4, hh = bh & 15;
  const int s0 = blockIdx.x * 64;
  const int t = threadIdx.x;
  const int tx = t & 63, ty = t >> 6;
  const bf16_t* src = qkv + (size_t)b * S_ * 3072 + 2048 + hh * 64;
  for (int r = ty; r < 64; r += 4)
    tile[r][tx] = src[(size_t)(s0 + r) * 3072 + tx];
  __syncthreads();
  bf16_t* dst = vT + (size_t)bh * 64 * 1024;
  for (int r = ty; r < 64; r += 4)
    dst[(size_t)r * 1024 + s0 + tx] = tile[tx][r];
}

// ---------------- flash attention (v2) ----------------
// KBLK=64, double-buffered K/V with prefetch issued BEFORE compute (loads fly
// under QK+softmax+PV, drained by the single end-of-tile barrier). Q fragments
// live in registers (staged once via LDS for coalescing). P buffer uses the
// stride-64 XOR swizzle. LDS = 16K(K) + 16K(V) + 8K(P) = 40960 B exactly
// -> 4 blocks/CU (vs 2 before). __launch_bounds__(256,4) pins VGPR<=128.
__global__ __launch_bounds__(256, 4) void flash_attn(
    const bf16_t* __restrict__ qkv, const bf16_t* __restrict__ vT,
    bf16_t* __restrict__ attn) {
  __shared__ __align__(16) bf16_t Ks[2][64 * 64];
  __shared__ __align__(16) bf16_t Vs[2][64 * 64];
  __shared__ __align__(16) bf16_t Ps[4][16 * 64];

  const int t = threadIdx.x;
  const int wave = t >> 6, lane = t & 63;
  const int lm = lane & 15, quad = lane >> 4;
  const int bh = blockIdx.y;
  const int b = bh >> 4, hh = bh & 15;
  const int s0 = blockIdx.x * 64;

  const bf16_t* qbase = qkv + (size_t)b * S_ * 3072 + hh * 64;
  const bf16_t* kbase = qbase + 1024;
  const bf16_t* vbase = vT + (size_t)bh * (64 * 1024);

  // staging geometry: thread t covers rows {t>>3, 32+(t>>3)}, chunk swizzle
  // cg = (t&7) ^ (row&7)  (identical for both halves since 32&7==0)
  const int row0 = t >> 3;
  const int cg = (t & 7) ^ (row0 & 7);
  const int o0 = t * 8, o1 = 2048 + t * 8;

  // prologue: Q -> Ks[1] (temp), K tile0 -> Ks[0], V tile0 -> Vs[0]
  async_copy16(qbase + (size_t)(s0 + row0) * 3072 + cg * 8, &Ks[1][o0]);
  async_copy16(qbase + (size_t)(s0 + 32 + row0) * 3072 + cg * 8, &Ks[1][o1]);
  async_copy16(kbase + (size_t)row0 * 3072 + cg * 8, &Ks[0][o0]);
  async_copy16(kbase + (size_t)(32 + row0) * 3072 + cg * 8, &Ks[0][o1]);
  async_copy16(vbase + (size_t)row0 * 1024 + cg * 8, &Vs[0][o0]);
  async_copy16(vbase + (size_t)(32 + row0) * 1024 + cg * 8, &Vs[0][o1]);
  __syncthreads();

  // Q fragments to registers: row = wave*16+lm, cols [0..31] and [32..63]
  bf16x8 aq0, aq1;
  {
    const int rq = wave * 16 + lm;
    const int rb = lm & 7;                // rq & 7
    aq0 = *(const bf16x8*)&Ks[1][rq * 64 + (quad ^ rb) * 8];
    aq1 = *(const bf16x8*)&Ks[1][rq * 64 + ((4 + quad) ^ rb) * 8];
  }
  __syncthreads();   // all waves done reading Q; Ks[1] reusable for tile 1

  f32x4 accO[4] = {};
  float mrow[4], lrow[4];
#pragma unroll
  for (int r = 0; r < 4; r++) { mrow[r] = -1e30f; lrow[r] = 0.f; }

  const float SC = 0.18033688f;           // 0.125 * log2(e): exp2 domain
  bf16_t* Pw = Ps[wave];
  const int rb = lm & 7;

  for (int tt = 0; tt < 16; ++tt) {
    const int cur = tt & 1;
    // prefetch next tile while this one computes
    if (tt < 15) {
      const int nb = cur ^ 1;
      const int k0n = (tt + 1) << 6;
      async_copy16(kbase + (size_t)(k0n + row0) * 3072 + cg * 8, &Ks[nb][o0]);
      async_copy16(kbase + (size_t)(k0n + 32 + row0) * 3072 + cg * 8, &Ks[nb][o1]);
      async_copy16(vbase + (size_t)row0 * 1024 + k0n + cg * 8, &Vs[nb][o0]);
      async_copy16(vbase + (size_t)(32 + row0) * 1024 + k0n + cg * 8, &Vs[nb][o1]);
    }

    // QK^T: accS[ni] holds S[q=quad*4+r][k=ni*16+lm] (raw, unscaled)
    f32x4 accS[4] = {};
    __builtin_amdgcn_s_setprio(1);
#pragma unroll
    for (int ni = 0; ni < 4; ni++) {
      const int rk = ni * 16 + lm;
      bf16x8 b0 = *(const bf16x8*)&Ks[cur][rk * 64 + ((quad ^ rb)) * 8];
      bf16x8 b1 = *(const bf16x8*)&Ks[cur][rk * 64 + (((4 + quad) ^ rb)) * 8];
      accS[ni] = __builtin_amdgcn_mfma_f32_16x16x32_bf16(aq0, b0, accS[ni], 0, 0, 0);
      accS[ni] = __builtin_amdgcn_mfma_f32_16x16x32_bf16(aq1, b1, accS[ni], 0, 0, 0);
    }
    __builtin_amdgcn_s_setprio(0);

    // online softmax (exp2 domain: m,l track SC-scaled scores)
    float alpha[4];
#pragma unroll
    for (int r = 0; r < 4; r++) {
      float mx = fmaxf(fmaxf(accS[0][r], accS[1][r]),
                       fmaxf(accS[2][r], accS[3][r])) * SC;
      mx = fmaxf(mx, __shfl_xor(mx, 1));
      mx = fmaxf(mx, __shfl_xor(mx, 2));
      mx = fmaxf(mx, __shfl_xor(mx, 4));
      mx = fmaxf(mx, __shfl_xor(mx, 8));
      float mnew = fmaxf(mrow[r], mx);
      alpha[r] = exp2f(mrow[r] - mnew);
      mrow[r] = mnew;
      float sum = 0.f;
#pragma unroll
      for (int ni = 0; ni < 4; ni++) {
        float p = exp2f(accS[ni][r] * SC - mnew);
        accS[ni][r] = p;
        sum += p;
      }
      sum += __shfl_xor(sum, 1);
      sum += __shfl_xor(sum, 2);
      sum += __shfl_xor(sum, 4);
      sum += __shfl_xor(sum, 8);
      lrow[r] = lrow[r] * alpha[r] + sum;
    }
#pragma unroll
    for (int di = 0; di < 4; di++)
#pragma unroll
      for (int r = 0; r < 4; r++) accO[di][r] *= alpha[r];

    // P -> LDS (per-wave, stride-64 XOR swizzle)
#pragma unroll
    for (int ni = 0; ni < 4; ni++)
#pragma unroll
      for (int r = 0; r < 4; r++) {
        int prow = quad * 4 + r;
        int col = ni * 16 + lm;
        Pw[prow * 64 + (((col >> 3) ^ (prow & 7)) << 3) + (col & 7)] =
            (__bf16)accS[ni][r];
      }

    // PV: A = P row lm, B = V^T row d
    {
      bf16x8 ap0 = *(const bf16x8*)&Pw[lm * 64 + ((quad ^ rb)) * 8];
      bf16x8 ap1 = *(const bf16x8*)&Pw[lm * 64 + (((4 + quad) ^ rb)) * 8];
      __builtin_amdgcn_s_setprio(1);
#pragma unroll
      for (int di = 0; di < 4; di++) {
        const int rv = di * 16 + lm;
        bf16x8 v0 = *(const bf16x8*)&Vs[cur][rv * 64 + ((quad ^ rb)) * 8];
        bf16x8 v1 = *(const bf16x8*)&Vs[cur][rv * 64 + (((4 + quad) ^ rb)) * 8];
        accO[di] = __builtin_amdgcn_mfma_f32_16x16x32_bf16(ap0, v0, accO[di], 0, 0, 0);
        accO[di] = __builtin_amdgcn_mfma_f32_16x16x32_bf16(ap1, v1, accO[di], 0, 0, 0);
      }
      __builtin_amdgcn_s_setprio(0);
    }
    __syncthreads();   // drains prefetch (vmcnt) + guards buffer reuse
  }

  // epilogue: normalize, stage O in Pw (same swizzle), vectorized store
#pragma unroll
  for (int r = 0; r < 4; r++) {
    float inv = 1.0f / lrow[r];
    int prow = quad * 4 + r;
#pragma unroll
    for (int di = 0; di < 4; di++) {
      int col = di * 16 + lm;
      int cph = (col >> 3) ^ (prow & 7);
      Pw[prow * 64 + cph * 8 + (col & 7)] = (__bf16)(accO[di][r] * inv);
    }
  }
  bf16_t* abase = attn + (size_t)b * S_ * 1024 +
                  (size_t)(s0 + wave * 16) * 1024 + hh * 64;
#pragma unroll
  for (int it = 0; it < 2; it++) {
    int slot = it * 64 + lane;
    int orow = slot >> 3;
    int gc = slot & 7;
    int cph = gc ^ (orow & 7);
    bf16x8 val = *(const bf16x8*)&Pw[orow * 64 + cph * 8];
    *(bf16x8*)(abase + (size_t)orow * 1024 + gc * 8) = val;
  }
}

// ---------------- generic C = A * B^T GEMM, pipelined double-buffer ----------------
// BK=32, 2 LDS buffers, one barrier per K-iter, loads issued after the barrier.
// LDS slot swizzle: slot s of row r holds global chunk s ^ ((r>>1)&3)
// (reader granule = 4*(lm&1) + quad^((lm>>1)&3): all 8 granules x2 -> conflict-free).
// XCD-aware block swizzle (requires gridDim.y == 32): per-XCD 8x4 patches.
// M,N multiples of 128; K multiple of 32.
// EPI: 0 = (+bias) -> bf16 ; 1 = *scale -> f32 ; 3 = gelu_tanh(acc+bias) -> bf16
template <int EPI>
__global__ __launch_bounds__(256) void gemm_bt(
    const bf16_t* __restrict__ A, int lda, long long sAz,
    const bf16_t* __restrict__ B, int ldb, long long sBz,
    void* __restrict__ Cv, int ldc, long long sCz,
    int M, int N, int K,
    const float* __restrict__ bias,
    float scale) {
  __shared__ __align__(16) bf16_t As[2][128 * 32];
  __shared__ __align__(16) bf16_t Bs[2][128 * 32];

  const int z = blockIdx.z;
  A += (size_t)z * sAz;
  B += (size_t)z * sBz;

  // XCD-aware swizzle: dispatch id d -> XCD d&7; give each XCD an 8x4 tile patch
  {
    int d = blockIdx.x + gridDim.x * blockIdx.y;
    int xcd = d & 7, sId = d >> 3;
    int qq = sId & 31, panel = sId >> 5;
    const int bx = panel * 8 + (qq >> 2);
    const int by = xcd * 4 + (qq & 3);
    // fallthrough uses m0/n0 below
    const int t = threadIdx.x;
    const int wave = t >> 6;
    const int lane = t & 63;
    const int lm = lane & 15;
    const int quad = lane >> 4;
    const int wr = wave >> 1;
    const int wc = wave & 1;

    const int m0 = by * 128;
    const int n0 = bx * 128;

    f32x4 acc[4][4] = {};

    // staging: thread t covers rows {t>>2, 64+(t>>2)}, LDS slot t&3 holds
    // global chunk (t&3) ^ ((srow>>1)&3)  [same for srow and srow+64]
    const int srow = t >> 2;
    const int gch = (t & 3) ^ ((srow >> 1) & 3);
    const int lds_off = t * 8;
    const bf16_t* Ap0 = A + (size_t)(m0 + srow) * lda + gch * 8;
    const bf16_t* Ap1 = A + (size_t)(m0 + 64 + srow) * lda + gch * 8;
    const bf16_t* Bp0 = B + (size_t)(n0 + srow) * ldb + gch * 8;
    const bf16_t* Bp1 = B + (size_t)(n0 + 64 + srow) * ldb + gch * 8;

    // reader slot offset: loop-invariant ((ra>>1)&3 == (lm>>1)&3)
    const int sOff = (quad ^ ((lm >> 1) & 3)) * 8;

    const int niter = K >> 5;
    async_copy16(Ap0, &As[0][lds_off]);
    async_copy16(Ap1, &As[0][2048 + lds_off]);
    async_copy16(Bp0, &Bs[0][lds_off]);
    async_copy16(Bp1, &Bs[0][2048 + lds_off]);

    for (int it = 0; it < niter; ++it) {
      asm volatile("s_waitcnt vmcnt(0)\n\ts_barrier" ::: "memory");
      if (it + 1 < niter) {
        const int ko = (it + 1) << 5;
        const int nb = (it + 1) & 1;
        async_copy16(Ap0 + ko, &As[nb][lds_off]);
        async_copy16(Ap1 + ko, &As[nb][2048 + lds_off]);
        async_copy16(Bp0 + ko, &Bs[nb][lds_off]);
        async_copy16(Bp1 + ko, &Bs[nb][2048 + lds_off]);
      }
      const int cb = it & 1;
      bf16x8 af[4], bfr[4];
#pragma unroll
      for (int i = 0; i < 4; i++) {
        af[i] = *(const bf16x8*)&As[cb][(wr * 64 + i * 16 + lm) * 32 + sOff];
        bfr[i] = *(const bf16x8*)&Bs[cb][(wc * 64 + i * 16 + lm) * 32 + sOff];
      }
#pragma unroll
      for (int mi = 0; mi < 4; mi++)
#pragma unroll
        for (int ni = 0; ni < 4; ni++)
          acc[mi][ni] = __builtin_amdgcn_mfma_f32_16x16x32_bf16(
              af[mi], bfr[ni], acc[mi][ni], 0, 0, 0);
    }

    const size_t cz = (size_t)z * sCz;
#pragma unroll
    for (int mi = 0; mi < 4; mi++) {
#pragma unroll
      for (int ni = 0; ni < 4; ni++) {
#pragma unroll
        for (int r = 0; r < 4; r++) {
          int row = m0 + wr * 64 + mi * 16 + quad * 4 + r;
          int col = n0 + wc * 64 + ni * 16 + lm;
          float v = acc[mi][ni][r];
          size_t idx = cz + (size_t)row * ldc + col;
          if (EPI == 1) {
            ((float*)Cv)[idx] = v * scale;
          } else if (EPI == 0) {
            if (bias) v += bias[col];
            ((bf16_t*)Cv)[idx] = (__bf16)v;
          } else if (EPI == 3) {
            v += bias[col];
            float u = 1.5957691216f * (v + 0.044715f * v * v * v);
            float g = v / (1.0f + __expf(-u));
            ((bf16_t*)Cv)[idx] = (__bf16)g;
          }
        }
      }
    }
  }
}

// ---------------- Wo split-K reduce + residual + LN2 + modulate ----------------
__global__ __launch_bounds__(256) void reduce_ln(
    const float* __restrict__ part, const float* __restrict__ x,
    const float* __restrict__ bo, const float* __restrict__ mod,
    float* __restrict__ x1, bf16_t* __restrict__ h) {
  const int row = blockIdx.x;
  const int b = row >> 10;
  const int t = threadIdx.x;
  const int c = t * 4;
  const size_t idx = (size_t)row * 1024 + c;
  float4 p0 = *(const float4*)(part + idx);
  float4 p1 = *(const float4*)(part + 4194304 + idx);
  float4 bb = *(const float4*)(bo + c);
  float4 al = *(const float4*)(mod + (size_t)b * 6144 + 2048 + c);
  float4 xs = *(const float4*)(x + idx);
  float4 xv;
  xv.x = xs.x + al.x * (p0.x + p1.x + bb.x);
  xv.y = xs.y + al.y * (p0.y + p1.y + bb.y);
  xv.z = xs.z + al.z * (p0.z + p1.z + bb.z);
  xv.w = xs.w + al.w * (p0.w + p1.w + bb.w);
  *(float4*)(x1 + idx) = xv;

  float s = xv.x + xv.y + xv.z + xv.w;
  float q = xv.x*xv.x + xv.y*xv.y + xv.z*xv.z + xv.w*xv.w;
  const int wave = t >> 6, lane = t & 63;
#pragma unroll
  for (int offs = 32; offs; offs >>= 1) {
    s += __shfl_down(s, offs);
    q += __shfl_down(q, offs);
  }
  __shared__ float sb[4][2];
  if (lane == 0) { sb[wave][0] = s; sb[wave][1] = q; }
  __syncthreads();
  float st = sb[0][0] + sb[1][0] + sb[2][0] + sb[3][0];
  float qt = sb[0][1] + sb[1][1] + sb[2][1] + sb[3][1];
  float mu = st * (1.0f / D_);
  float var = qt * (1.0f / D_) - mu * mu;
  float rstd = rsqrtf(var + 1e-6f);
  const float* mb = mod + (size_t)b * 6144 + 3072;
  float4 gm = *(const float4*)(mb + c);
  float4 bt = *(const float4*)(mb + 1024 + c);
  bf16x4 pk;
  pk.x = (__bf16)((xv.x - mu) * rstd * (1.0f + bt.x) + gm.x);
  pk.y = (__bf16)((xv.y - mu) * rstd * (1.0f + bt.y) + gm.y);
  pk.z = (__bf16)((xv.z - mu) * rstd * (1.0f + bt.z) + gm.z);
  pk.w = (__bf16)((xv.w - mu) * rstd * (1.0f + bt.w) + gm.w);
  *(bf16x4*)(h + idx) = pk;
}

// ---------------- W2 split-K(2) reduction + epilogue ----------------
__global__ __launch_bounds__(256) void reduce_w2(
    const float* __restrict__ part, const float* __restrict__ x1,
    const float* __restrict__ b2, const float* __restrict__ mod,
    float* __restrict__ out) {
  const int idx = (blockIdx.x * 256 + threadIdx.x) * 4;
  const int col = idx & 1023;
  const int row = idx >> 10;
  const int b = row >> 10;
  float4 s0 = *(const float4*)(part + idx);
  float4 s1 = *(const float4*)(part + 4194304 + idx);
  float4 bb = *(const float4*)(b2 + col);
  float4 al = *(const float4*)(mod + (size_t)b * 6144 + 5120 + col);
  float4 rs = *(const float4*)(x1 + idx);
  float4 o;
  o.x = rs.x + al.x * (s0.x + s1.x + bb.x);
  o.y = rs.y + al.y * (s0.y + s1.y + bb.y);
  o.z = rs.z + al.z * (s0.z + s1.z + bb.z);
  o.w = rs.w + al.w * (s0.w + s1.w + bb.w);
  *(float4*)(out + idx) = o;
}

extern "C" void kernel_launch(void* const* d_in, const int* in_sizes, int n_in,
                              void* d_out, int out_size, void* d_ws, size_t ws_size,
                              hipStream_t stream) {
  (void)in_sizes; (void)n_in; (void)out_size; (void)ws_size;
  const float* x    = (const float*)d_in[0];
  const float* cond = (const float*)d_in[1];
  const float* Wq   = (const float*)d_in[2];
  const float* bq   = (const float*)d_in[3];
  const float* Wk   = (const float*)d_in[4];
  const float* bk   = (const float*)d_in[5];
  const float* Wv   = (const float*)d_in[6];
  const float* bv   = (const float*)d_in[7];
  const float* Wo   = (const float*)d_in[8];
  const float* bo   = (const float*)d_in[9];
  const float* W1   = (const float*)d_in[10];
  const float* b1   = (const float*)d_in[11];
  const float* W2   = (const float*)d_in[12];
  const float* b2   = (const float*)d_in[13];
  const float* Wada = (const float*)d_in[14];
  const float* bada = (const float*)d_in[15];

  uint8_t* ws = (uint8_t*)d_ws;
  bf16_t* wbf   = (bf16_t*)(ws + OFF_WBF);
  float*  bqkv  = (float*)(ws + OFF_BQKV);
  float*  mod   = (float*)(ws + OFF_MOD);
  bf16_t* h     = (bf16_t*)(ws + OFF_H);
  bf16_t* qkv   = (bf16_t*)(ws + OFF_QKV);
  bf16_t* vT    = (bf16_t*)(ws + OFF_VT);
  bf16_t* attn  = (bf16_t*)(ws + OFF_ATTN);
  float*  x1    = (float*)(ws + OFF_X1);
  float*  part  = (float*)(ws + OFF_PART);
  bf16_t* mlph  = (bf16_t*)(ws + OFF_MLPH);
  float* out = (float*)d_out;

  convert_pack<<<dim3(4096, 7, 1), 256, 0, stream>>>(Wq, Wk, Wv, Wo, W1, W2,
                                                     bq, bk, bv, wbf, bqkv);
  ada_mod<<<1536, 256, 0, stream>>>(cond, Wada, bada, mod);
  ln_modulate<<<4096, 256, 0, stream>>>(x, mod, h, 0);
  // qkv = h @ [Wq;Wk;Wv]^T + bias
  gemm_bt<0><<<dim3(24, 32, 1), 256, 0, stream>>>(
      h, 1024, 0, wbf, 1024, 0, qkv, 3072, 0, 4096, 3072, 1024,
      bqkv, 1.f);
  transpose_v<<<dim3(16, 64, 1), 256, 0, stream>>>(qkv, vT);
  flash_attn<<<dim3(16, 64, 1), 256, 0, stream>>>(qkv, vT, attn);

  // Wo split-K=2: part[z] = attn[:, z*512:] @ Wo[:, z*512:]^T
  gemm_bt<1><<<dim3(8, 32, 2), 256, 0, stream>>>(
      attn, 1024, 512, wbf + (size_t)3 * MEG, 1024, 512, part, 1024, 4194304,
      4096, 1024, 512, nullptr, 1.f);
  // x1 = x + alpha1*(sum part + bo); h = modulate(ln(x1), beta2, gama2)
  reduce_ln<<<4096, 256, 0, stream>>>(part, x, bo, mod, x1, h);

  // mlph = gelu(h @ W1^T + b1)
  gemm_bt<3><<<dim3(32, 32, 1), 256, 0, stream>>>(
      h, 1024, 0, wbf + (size_t)4 * MEG, 1024, 0, mlph, 4096, 0,
      4096, 4096, 1024, b1, 1.f);
  // W2 split-K=2
  gemm_bt<1><<<dim3(8, 32, 2), 256, 0, stream>>>(
      mlph, 4096, 2048, wbf + (size_t)8 * MEG, 4096, 2048, part, 1024, 4194304,
      4096, 1024, 2048, nullptr, 1.f);
  reduce_w2<<<4096, 256, 0, stream>>>(part, x1, b2, mod, out);
}

// Round 2
// 404.364 us; speedup vs baseline: 1.0109x; 1.0046x over previous
//
#include <hip/hip_runtime.h>
#include <cstdint>

typedef __bf16 bf16_t;
typedef __bf16 bf16x4 __attribute__((ext_vector_type(4)));
typedef __bf16 bf16x8 __attribute__((ext_vector_type(8)));
typedef float f32x4 __attribute__((ext_vector_type(4)));

#define B_ 4
#define S_ 1024
#define D_ 1024
#define HID_ 4096
#define MEG (1u << 20)

// ---------------- workspace layout (bytes) ----------------
static const size_t OFF_WBF  = 0;                 // 12M bf16 (Wq,Wk,Wv,Wo,W1,W2)
static const size_t OFF_BQKV = 25165824;          // 3072 f32
static const size_t OFF_MOD  = 25178112;          // 4*6144 f32
static const size_t OFF_H    = 25276416;          // 4096*1024 bf16
static const size_t OFF_QKV  = 33665024;          // 4096*3072 bf16
static const size_t OFF_VT   = 58830848;          // 4*16*64*1024 bf16
static const size_t OFF_ATTN = 67219456;          // 4096*1024 bf16
static const size_t OFF_X1   = 75608064;          // 4096*1024 f32
static const size_t OFF_PART = 92385280;          // 2 * 4096*1024 f32 (split-K partials)
static const size_t OFF_MLPH = 159494144;         // 4096*4096 bf16 = 32MB

// ---------------- async global->LDS (16B/lane) ----------------
__device__ __forceinline__ void async_copy16(const bf16_t* g, bf16_t* l) {
  __builtin_amdgcn_global_load_lds(
      (__attribute__((address_space(1))) void*)(g),
      (__attribute__((address_space(3))) void*)(l), 16, 0, 0);
}

// ---------------- weight convert + bias pack ----------------
__global__ __launch_bounds__(256) void convert_pack(
    const float* __restrict__ Wq, const float* __restrict__ Wk,
    const float* __restrict__ Wv, const float* __restrict__ Wo,
    const float* __restrict__ W1, const float* __restrict__ W2,
    const float* __restrict__ bq, const float* __restrict__ bk,
    const float* __restrict__ bv, bf16_t* __restrict__ wbf,
    float* __restrict__ bqkv) {
  const int y = blockIdx.y;
  if (y == 6) {
    int i = blockIdx.x * 256 + threadIdx.x;
    if (i < 3072)
      bqkv[i] = i < 1024 ? bq[i] : (i < 2048 ? bk[i - 1024] : bv[i - 2048]);
    return;
  }
  const float* src; bf16_t* dst; int n;
  switch (y) {
    case 0: src = Wq; dst = wbf;           n = MEG;     break;
    case 1: src = Wk; dst = wbf + MEG;     n = MEG;     break;
    case 2: src = Wv; dst = wbf + 2*MEG;   n = MEG;     break;
    case 3: src = Wo; dst = wbf + 3*MEG;   n = MEG;     break;
    case 4: src = W1; dst = wbf + 4*MEG;   n = 4*MEG;   break;
    default: src = W2; dst = wbf + 8*MEG;  n = 4*MEG;   break;
  }
  int idx = (blockIdx.x * 256 + threadIdx.x) * 4;
  if (idx < n) {
    float4 v = *(const float4*)(src + idx);
    bf16x4 pk;
    pk.x = (__bf16)v.x; pk.y = (__bf16)v.y; pk.z = (__bf16)v.z; pk.w = (__bf16)v.w;
    *(bf16x4*)(dst + idx) = pk;
  }
}

// ---------------- adaLN: one wave per output o, all 4 batches ----------------
__global__ __launch_bounds__(256) void ada_mod(
    const float* __restrict__ cond, const float* __restrict__ Wada,
    const float* __restrict__ bada, float* __restrict__ mod) {
  const int wave = threadIdx.x >> 6, lane = threadIdx.x & 63;
  const int o = blockIdx.x * 4 + wave;      // 0..6143
  const float* wr = Wada + (size_t)o * D_;
  float a0 = 0.f, a1 = 0.f, a2 = 0.f, a3 = 0.f;
#pragma unroll
  for (int l = 0; l < 16; l++) {
    int i = l * 64 + lane;
    float w = wr[i];
    float c0 = cond[i], c1 = cond[1024 + i], c2 = cond[2048 + i], c3 = cond[3072 + i];
    a0 += w * (c0 / (1.0f + __expf(-c0)));
    a1 += w * (c1 / (1.0f + __expf(-c1)));
    a2 += w * (c2 / (1.0f + __expf(-c2)));
    a3 += w * (c3 / (1.0f + __expf(-c3)));
  }
#pragma unroll
  for (int offs = 32; offs; offs >>= 1) {
    a0 += __shfl_xor(a0, offs);
    a1 += __shfl_xor(a1, offs);
    a2 += __shfl_xor(a2, offs);
    a3 += __shfl_xor(a3, offs);
  }
  if (lane == 0) {
    float bb = bada[o];
    mod[o]          = a0 + bb;
    mod[6144 + o]   = a1 + bb;
    mod[12288 + o]  = a2 + bb;
    mod[18432 + o]  = a3 + bb;
  }
}

// ---------------- LayerNorm + modulate -> bf16 ----------------
__global__ __launch_bounds__(256) void ln_modulate(
    const float* __restrict__ X, const float* __restrict__ mod,
    bf16_t* __restrict__ H, int goff) {
  const int row = blockIdx.x;
  const int b = row >> 10;
  const int t = threadIdx.x;
  const float* xr = X + (size_t)row * D_;
  float4 xv = *(const float4*)(xr + t * 4);
  float s = xv.x + xv.y + xv.z + xv.w;
  float q = xv.x*xv.x + xv.y*xv.y + xv.z*xv.z + xv.w*xv.w;
  const int wave = t >> 6, lane = t & 63;
#pragma unroll
  for (int offs = 32; offs; offs >>= 1) {
    s += __shfl_down(s, offs);
    q += __shfl_down(q, offs);
  }
  __shared__ float sb[4][2];
  if (lane == 0) { sb[wave][0] = s; sb[wave][1] = q; }
  __syncthreads();
  float st = sb[0][0] + sb[1][0] + sb[2][0] + sb[3][0];
  float qt = sb[0][1] + sb[1][1] + sb[2][1] + sb[3][1];
  float mu = st * (1.0f / D_);
  float var = qt * (1.0f / D_) - mu * mu;
  float rstd = rsqrtf(var + 1e-6f);
  const float* mb = mod + (size_t)b * 6144 + goff;
  const int c = t * 4;
  float4 gm = *(const float4*)(mb + c);
  float4 bt = *(const float4*)(mb + 1024 + c);
  bf16x4 pk;
  pk.x = (__bf16)((xv.x - mu) * rstd * (1.0f + bt.x) + gm.x);
  pk.y = (__bf16)((xv.y - mu) * rstd * (1.0f + bt.y) + gm.y);
  pk.z = (__bf16)((xv.z - mu) * rstd * (1.0f + bt.z) + gm.z);
  pk.w = (__bf16)((xv.w - mu) * rstd * (1.0f + bt.w) + gm.w);
  *(bf16x4*)(H + (size_t)row * D_ + c) = pk;
}

// ---------------- V transpose: vT[b,h,d,s] <- qkv[b,s, 2048+h*64+d] ----------------
__global__ __launch_bounds__(256) void transpose_v(
    const bf16_t* __restrict__ qkv, bf16_t* __restrict__ vT) {
  __shared__ bf16_t tile[64][65];
  const int bh = blockIdx.y;
  const int b = bh >> 4, hh = bh & 15;
  const int s0 = blockIdx.x * 64;
  const int t = threadIdx.x;
  const int tx = t & 63, ty = t >> 6;
  const bf16_t* src = qkv + (size_t)b * S_ * 3072 + 2048 + hh * 64;
  for (int r = ty; r < 64; r += 4)
    tile[r][tx] = src[(size_t)(s0 + r) * 3072 + tx];
  __syncthreads();
  bf16_t* dst = vT + (size_t)bh * 64 * 1024;
  for (int r = ty; r < 64; r += 4)
    dst[(size_t)r * 1024 + s0 + tx] = tile[tx][r];
}

// ---------------- flash attention (v3) ----------------
// KBLK=128 softmax granularity (8 iterations, halves per-tile serial overhead
// vs v2), staged as 2x 64x64 sub-tiles reusing v2's zero-conflict XOR layouts.
// K/V double-buffered, prefetch issued before compute (one vmcnt(0)+barrier
// per 128-tile). Q in registers. T13 defer-max (THR=8 in exp2 domain) skips
// the alpha/rescale pass when the running max doesn't grow.
// LDS = 32K(K) + 32K(V) + 16K(P) = 80KB -> 2 blocks/CU.
__global__ __launch_bounds__(256) void flash_attn(
    const bf16_t* __restrict__ qkv, const bf16_t* __restrict__ vT,
    bf16_t* __restrict__ attn) {
  __shared__ __align__(16) bf16_t Ks[2][2][64 * 64];
  __shared__ __align__(16) bf16_t Vs[2][2][64 * 64];
  __shared__ __align__(16) bf16_t Ps[4][2][16 * 64];

  const int t = threadIdx.x;
  const int wave = t >> 6, lane = t & 63;
  const int lm = lane & 15, quad = lane >> 4;
  const int bh = blockIdx.y;
  const int b = bh >> 4, hh = bh & 15;
  const int s0 = blockIdx.x * 64;

  const bf16_t* qbase = qkv + (size_t)b * S_ * 3072 + hh * 64;
  const bf16_t* kbase = qbase + 1024;
  const bf16_t* vbase = vT + (size_t)bh * (64 * 1024);

  // staging geometry (v2): thread t covers rows {t>>3, 32+(t>>3)} of a 64x64
  // sub-tile; LDS slot (t&7) holds global chunk cg = (t&7)^(row&7)
  const int row0 = t >> 3;
  const int cg = (t & 7) ^ (row0 & 7);
  const int o0 = t * 8, o1 = 2048 + t * 8;
  const bf16_t* kr = kbase + (size_t)row0 * 3072 + cg * 8;   // +k*3072 per row
  const bf16_t* vr0 = vbase + (size_t)row0 * 1024 + cg * 8;  // +s offset
  const bf16_t* vr1 = vbase + (size_t)(32 + row0) * 1024 + cg * 8;

  // prologue: Q -> Ks[1][0] (temp), K tile0 (128 rows) -> Ks[0][0..1],
  // V tile0 -> Vs[0][0..1]
  async_copy16(qbase + (size_t)(s0 + row0) * 3072 + cg * 8, &Ks[1][0][o0]);
  async_copy16(qbase + (size_t)(s0 + 32 + row0) * 3072 + cg * 8, &Ks[1][0][o1]);
  async_copy16(kr, &Ks[0][0][o0]);
  async_copy16(kr + (size_t)32 * 3072, &Ks[0][0][o1]);
  async_copy16(kr + (size_t)64 * 3072, &Ks[0][1][o0]);
  async_copy16(kr + (size_t)96 * 3072, &Ks[0][1][o1]);
  async_copy16(vr0, &Vs[0][0][o0]);
  async_copy16(vr1, &Vs[0][0][o1]);
  async_copy16(vr0 + 64, &Vs[0][1][o0]);
  async_copy16(vr1 + 64, &Vs[0][1][o1]);
  __syncthreads();

  // Q fragments to registers: row = wave*16+lm, cols [0..31] and [32..63]
  bf16x8 aq0, aq1;
  {
    const int rq = wave * 16 + lm;
    const int rbq = lm & 7;               // rq & 7
    aq0 = *(const bf16x8*)&Ks[1][0][rq * 64 + (quad ^ rbq) * 8];
    aq1 = *(const bf16x8*)&Ks[1][0][rq * 64 + ((4 + quad) ^ rbq) * 8];
  }
  __syncthreads();   // all waves done reading Q; Ks[1] reusable for tile 1

  f32x4 accO[4] = {};
  float mrow[4], lrow[4];
#pragma unroll
  for (int r = 0; r < 4; r++) { mrow[r] = -1e30f; lrow[r] = 0.f; }

  const float SC = 0.18033688f;           // 0.125 * log2(e): exp2 domain
  const int rb = lm & 7;

  for (int tt = 0; tt < 8; ++tt) {
    const int cur = tt & 1;
    // prefetch next 128-wide tile while this one computes
    if (tt < 7) {
      const int nb = cur ^ 1;
      const size_t k0n = (size_t)(tt + 1) << 7;
      const bf16_t* kn = kr + k0n * 3072;
      async_copy16(kn, &Ks[nb][0][o0]);
      async_copy16(kn + (size_t)32 * 3072, &Ks[nb][0][o1]);
      async_copy16(kn + (size_t)64 * 3072, &Ks[nb][1][o0]);
      async_copy16(kn + (size_t)96 * 3072, &Ks[nb][1][o1]);
      async_copy16(vr0 + k0n, &Vs[nb][0][o0]);
      async_copy16(vr1 + k0n, &Vs[nb][0][o1]);
      async_copy16(vr0 + k0n + 64, &Vs[nb][1][o0]);
      async_copy16(vr1 + k0n + 64, &Vs[nb][1][o1]);
    }

    // QK^T: accS[j] holds S[q=quad*4+r][k = j*16 + lm + 64*(j>>2)] style:
    // global k-col of accS[j] = (j>>2)*64 + (j&3)*16 + lm
    f32x4 accS[8];
#pragma unroll
    for (int j = 0; j < 8; j++) accS[j] = (f32x4){0.f, 0.f, 0.f, 0.f};
    __builtin_amdgcn_s_setprio(1);
#pragma unroll
    for (int h = 0; h < 2; h++) {
#pragma unroll
      for (int ni = 0; ni < 4; ni++) {
        const int rk = ni * 16 + lm;
        bf16x8 b0 = *(const bf16x8*)&Ks[cur][h][rk * 64 + ((quad ^ rb)) * 8];
        bf16x8 b1 = *(const bf16x8*)&Ks[cur][h][rk * 64 + (((4 + quad) ^ rb)) * 8];
        f32x4 a = accS[h * 4 + ni];
        a = __builtin_amdgcn_mfma_f32_16x16x32_bf16(aq0, b0, a, 0, 0, 0);
        a = __builtin_amdgcn_mfma_f32_16x16x32_bf16(aq1, b1, a, 0, 0, 0);
        accS[h * 4 + ni] = a;
      }
    }
    __builtin_amdgcn_s_setprio(0);

    // one softmax pass per 128 columns; T13 defer-max with THR=8
    float mx[4];
#pragma unroll
    for (int r = 0; r < 4; r++) {
      float m0 = fmaxf(fmaxf(accS[0][r], accS[1][r]), fmaxf(accS[2][r], accS[3][r]));
      float m1 = fmaxf(fmaxf(accS[4][r], accS[5][r]), fmaxf(accS[6][r], accS[7][r]));
      float m8 = fmaxf(m0, m1);
      m8 = fmaxf(m8, __shfl_xor(m8, 1));
      m8 = fmaxf(m8, __shfl_xor(m8, 2));
      m8 = fmaxf(m8, __shfl_xor(m8, 4));
      m8 = fmaxf(m8, __shfl_xor(m8, 8));
      mx[r] = m8 * SC;
    }
    bool ok = (mx[0] - mrow[0] <= 8.0f) && (mx[1] - mrow[1] <= 8.0f) &&
              (mx[2] - mrow[2] <= 8.0f) && (mx[3] - mrow[3] <= 8.0f);
    if (!__all(ok)) {
#pragma unroll
      for (int r = 0; r < 4; r++) {
        float mnew = fmaxf(mrow[r], mx[r]);
        float al = exp2f(mrow[r] - mnew);
        mrow[r] = mnew;
        lrow[r] *= al;
#pragma unroll
        for (int di = 0; di < 4; di++) accO[di][r] *= al;
      }
    }
#pragma unroll
    for (int r = 0; r < 4; r++) {
      float sum = 0.f;
#pragma unroll
      for (int j = 0; j < 8; j++) {
        float p = exp2f(accS[j][r] * SC - mrow[r]);
        accS[j][r] = p;
        sum += p;
      }
      sum += __shfl_xor(sum, 1);
      sum += __shfl_xor(sum, 2);
      sum += __shfl_xor(sum, 4);
      sum += __shfl_xor(sum, 8);
      lrow[r] += sum;
    }

    // P -> LDS (per-wave, two 64-wide halves, v2 swizzle)
#pragma unroll
    for (int j = 0; j < 8; j++)
#pragma unroll
      for (int r = 0; r < 4; r++) {
        int prow = quad * 4 + r;
        int c = (j & 3) * 16 + lm;
        Ps[wave][j >> 2][prow * 64 + (((c >> 3) ^ (prow & 7)) << 3) + (c & 7)] =
            (__bf16)accS[j][r];
      }

    // PV over 128 k: 4 slices of 32
    __builtin_amdgcn_s_setprio(1);
#pragma unroll
    for (int ks = 0; ks < 4; ks++) {
      const int half = ks >> 1, loc = ks & 1;
      bf16x8 ap = *(const bf16x8*)&Ps[wave][half]
          [lm * 64 + (((loc * 4 + quad) ^ rb)) * 8];
#pragma unroll
      for (int di = 0; di < 4; di++) {
        const int rv = di * 16 + lm;
        bf16x8 vv = *(const bf16x8*)&Vs[cur][half]
            [rv * 64 + (((loc * 4 + quad) ^ rb)) * 8];
        accO[di] = __builtin_amdgcn_mfma_f32_16x16x32_bf16(ap, vv, accO[di], 0, 0, 0);
      }
    }
    __builtin_amdgcn_s_setprio(0);
    __syncthreads();   // drains prefetch (vmcnt) + guards buffer swap
  }

  // epilogue: normalize, stage O in Ps[wave][0] (same swizzle), vector store
#pragma unroll
  for (int r = 0; r < 4; r++) {
    float inv = 1.0f / lrow[r];
    int prow = quad * 4 + r;
#pragma unroll
    for (int di = 0; di < 4; di++) {
      int col = di * 16 + lm;
      int cph = (col >> 3) ^ (prow & 7);
      Ps[wave][0][prow * 64 + cph * 8 + (col & 7)] = (__bf16)(accO[di][r] * inv);
    }
  }
  bf16_t* abase = attn + (size_t)b * S_ * 1024 +
                  (size_t)(s0 + wave * 16) * 1024 + hh * 64;
#pragma unroll
  for (int it = 0; it < 2; it++) {
    int slot = it * 64 + lane;
    int orow = slot >> 3;
    int gc = slot & 7;
    int cph = gc ^ (orow & 7);
    bf16x8 val = *(const bf16x8*)&Ps[wave][0][orow * 64 + cph * 8];
    *(bf16x8*)(abase + (size_t)orow * 1024 + gc * 8) = val;
  }
}

// ---------------- generic C = A * B^T GEMM, pipelined double-buffer ----------------
// BK=32, 2 LDS buffers, one barrier per K-iter, loads issued after the barrier.
// LDS slot swizzle: slot s of row r holds global chunk s ^ ((r>>1)&3)
// (reader granule = 4*(lm&1) + quad^((lm>>1)&3): all 8 granules x2 -> conflict-free).
// XCD-aware block swizzle (requires gridDim.y == 32): per-XCD 8x4 patches.
// M,N multiples of 128; K multiple of 32.
// EPI: 0 = (+bias) -> bf16 ; 1 = *scale -> f32 ; 3 = gelu_tanh(acc+bias) -> bf16
template <int EPI>
__global__ __launch_bounds__(256) void gemm_bt(
    const bf16_t* __restrict__ A, int lda, long long sAz,
    const bf16_t* __restrict__ B, int ldb, long long sBz,
    void* __restrict__ Cv, int ldc, long long sCz,
    int M, int N, int K,
    const float* __restrict__ bias,
    float scale) {
  __shared__ __align__(16) bf16_t As[2][128 * 32];
  __shared__ __align__(16) bf16_t Bs[2][128 * 32];

  const int z = blockIdx.z;
  A += (size_t)z * sAz;
  B += (size_t)z * sBz;

  // XCD-aware swizzle: dispatch id d -> XCD d&7; give each XCD an 8x4 tile patch
  {
    int d = blockIdx.x + gridDim.x * blockIdx.y;
    int xcd = d & 7, sId = d >> 3;
    int qq = sId & 31, panel = sId >> 5;
    const int bx = panel * 8 + (qq >> 2);
    const int by = xcd * 4 + (qq & 3);
    // fallthrough uses m0/n0 below
    const int t = threadIdx.x;
    const int wave = t >> 6;
    const int lane = t & 63;
    const int lm = lane & 15;
    const int quad = lane >> 4;
    const int wr = wave >> 1;
    const int wc = wave & 1;

    const int m0 = by * 128;
    const int n0 = bx * 128;

    f32x4 acc[4][4] = {};

    // staging: thread t covers rows {t>>2, 64+(t>>2)}, LDS slot t&3 holds
    // global chunk (t&3) ^ ((srow>>1)&3)  [same for srow and srow+64]
    const int srow = t >> 2;
    const int gch = (t & 3) ^ ((srow >> 1) & 3);
    const int lds_off = t * 8;
    const bf16_t* Ap0 = A + (size_t)(m0 + srow) * lda + gch * 8;
    const bf16_t* Ap1 = A + (size_t)(m0 + 64 + srow) * lda + gch * 8;
    const bf16_t* Bp0 = B + (size_t)(n0 + srow) * ldb + gch * 8;
    const bf16_t* Bp1 = B + (size_t)(n0 + 64 + srow) * ldb + gch * 8;

    // reader slot offset: loop-invariant ((ra>>1)&3 == (lm>>1)&3)
    const int sOff = (quad ^ ((lm >> 1) & 3)) * 8;

    const int niter = K >> 5;
    async_copy16(Ap0, &As[0][lds_off]);
    async_copy16(Ap1, &As[0][2048 + lds_off]);
    async_copy16(Bp0, &Bs[0][lds_off]);
    async_copy16(Bp1, &Bs[0][2048 + lds_off]);

    for (int it = 0; it < niter; ++it) {
      asm volatile("s_waitcnt vmcnt(0)\n\ts_barrier" ::: "memory");
      if (it + 1 < niter) {
        const int ko = (it + 1) << 5;
        const int nb = (it + 1) & 1;
        async_copy16(Ap0 + ko, &As[nb][lds_off]);
        async_copy16(Ap1 + ko, &As[nb][2048 + lds_off]);
        async_copy16(Bp0 + ko, &Bs[nb][lds_off]);
        async_copy16(Bp1 + ko, &Bs[nb][2048 + lds_off]);
      }
      const int cb = it & 1;
      bf16x8 af[4], bfr[4];
#pragma unroll
      for (int i = 0; i < 4; i++) {
        af[i] = *(const bf16x8*)&As[cb][(wr * 64 + i * 16 + lm) * 32 + sOff];
        bfr[i] = *(const bf16x8*)&Bs[cb][(wc * 64 + i * 16 + lm) * 32 + sOff];
      }
#pragma unroll
      for (int mi = 0; mi < 4; mi++)
#pragma unroll
        for (int ni = 0; ni < 4; ni++)
          acc[mi][ni] = __builtin_amdgcn_mfma_f32_16x16x32_bf16(
              af[mi], bfr[ni], acc[mi][ni], 0, 0, 0);
    }

    const size_t cz = (size_t)z * sCz;
#pragma unroll
    for (int mi = 0; mi < 4; mi++) {
#pragma unroll
      for (int ni = 0; ni < 4; ni++) {
#pragma unroll
        for (int r = 0; r < 4; r++) {
          int row = m0 + wr * 64 + mi * 16 + quad * 4 + r;
          int col = n0 + wc * 64 + ni * 16 + lm;
          float v = acc[mi][ni][r];
          size_t idx = cz + (size_t)row * ldc + col;
          if (EPI == 1) {
            ((float*)Cv)[idx] = v * scale;
          } else if (EPI == 0) {
            if (bias) v += bias[col];
            ((bf16_t*)Cv)[idx] = (__bf16)v;
          } else if (EPI == 3) {
            v += bias[col];
            float u = 1.5957691216f * (v + 0.044715f * v * v * v);
            float g = v / (1.0f + __expf(-u));
            ((bf16_t*)Cv)[idx] = (__bf16)g;
          }
        }
      }
    }
  }
}

// ---------------- Wo split-K reduce + residual + LN2 + modulate ----------------
__global__ __launch_bounds__(256) void reduce_ln(
    const float* __restrict__ part, const float* __restrict__ x,
    const float* __restrict__ bo, const float* __restrict__ mod,
    float* __restrict__ x1, bf16_t* __restrict__ h) {
  const int row = blockIdx.x;
  const int b = row >> 10;
  const int t = threadIdx.x;
  const int c = t * 4;
  const size_t idx = (size_t)row * 1024 + c;
  float4 p0 = *(const float4*)(part + idx);
  float4 p1 = *(const float4*)(part + 4194304 + idx);
  float4 bb = *(const float4*)(bo + c);
  float4 al = *(const float4*)(mod + (size_t)b * 6144 + 2048 + c);
  float4 xs = *(const float4*)(x + idx);
  float4 xv;
  xv.x = xs.x + al.x * (p0.x + p1.x + bb.x);
  xv.y = xs.y + al.y * (p0.y + p1.y + bb.y);
  xv.z = xs.z + al.z * (p0.z + p1.z + bb.z);
  xv.w = xs.w + al.w * (p0.w + p1.w + bb.w);
  *(float4*)(x1 + idx) = xv;

  float s = xv.x + xv.y + xv.z + xv.w;
  float q = xv.x*xv.x + xv.y*xv.y + xv.z*xv.z + xv.w*xv.w;
  const int wave = t >> 6, lane = t & 63;
#pragma unroll
  for (int offs = 32; offs; offs >>= 1) {
    s += __shfl_down(s, offs);
    q += __shfl_down(q, offs);
  }
  __shared__ float sb[4][2];
  if (lane == 0) { sb[wave][0] = s; sb[wave][1] = q; }
  __syncthreads();
  float st = sb[0][0] + sb[1][0] + sb[2][0] + sb[3][0];
  float qt = sb[0][1] + sb[1][1] + sb[2][1] + sb[3][1];
  float mu = st * (1.0f / D_);
  float var = qt * (1.0f / D_) - mu * mu;
  float rstd = rsqrtf(var + 1e-6f);
  const float* mb = mod + (size_t)b * 6144 + 3072;
  float4 gm = *(const float4*)(mb + c);
  float4 bt = *(const float4*)(mb + 1024 + c);
  bf16x4 pk;
  pk.x = (__bf16)((xv.x - mu) * rstd * (1.0f + bt.x) + gm.x);
  pk.y = (__bf16)((xv.y - mu) * rstd * (1.0f + bt.y) + gm.y);
  pk.z = (__bf16)((xv.z - mu) * rstd * (1.0f + bt.z) + gm.z);
  pk.w = (__bf16)((xv.w - mu) * rstd * (1.0f + bt.w) + gm.w);
  *(bf16x4*)(h + idx) = pk;
}

// ---------------- W2 split-K(2) reduction + epilogue ----------------
__global__ __launch_bounds__(256) void reduce_w2(
    const float* __restrict__ part, const float* __restrict__ x1,
    const float* __restrict__ b2, const float* __restrict__ mod,
    float* __restrict__ out) {
  const int idx = (blockIdx.x * 256 + threadIdx.x) * 4;
  const int col = idx & 1023;
  const int row = idx >> 10;
  const int b = row >> 10;
  float4 s0 = *(const float4*)(part + idx);
  float4 s1 = *(const float4*)(part + 4194304 + idx);
  float4 bb = *(const float4*)(b2 + col);
  float4 al = *(const float4*)(mod + (size_t)b * 6144 + 5120 + col);
  float4 rs = *(const float4*)(x1 + idx);
  float4 o;
  o.x = rs.x + al.x * (s0.x + s1.x + bb.x);
  o.y = rs.y + al.y * (s0.y + s1.y + bb.y);
  o.z = rs.z + al.z * (s0.z + s1.z + bb.z);
  o.w = rs.w + al.w * (s0.w + s1.w + bb.w);
  *(float4*)(out + idx) = o;
}

extern "C" void kernel_launch(void* const* d_in, const int* in_sizes, int n_in,
                              void* d_out, int out_size, void* d_ws, size_t ws_size,
                              hipStream_t stream) {
  (void)in_sizes; (void)n_in; (void)out_size; (void)ws_size;
  const float* x    = (const float*)d_in[0];
  const float* cond = (const float*)d_in[1];
  const float* Wq   = (const float*)d_in[2];
  const float* bq   = (const float*)d_in[3];
  const float* Wk   = (const float*)d_in[4];
  const float* bk   = (const float*)d_in[5];
  const float* Wv   = (const float*)d_in[6];
  const float* bv   = (const float*)d_in[7];
  const float* Wo   = (const float*)d_in[8];
  const float* bo   = (const float*)d_in[9];
  const float* W1   = (const float*)d_in[10];
  const float* b1   = (const float*)d_in[11];
  const float* W2   = (const float*)d_in[12];
  const float* b2   = (const float*)d_in[13];
  const float* Wada = (const float*)d_in[14];
  const float* bada = (const float*)d_in[15];

  uint8_t* ws = (uint8_t*)d_ws;
  bf16_t* wbf   = (bf16_t*)(ws + OFF_WBF);
  float*  bqkv  = (float*)(ws + OFF_BQKV);
  float*  mod   = (float*)(ws + OFF_MOD);
  bf16_t* h     = (bf16_t*)(ws + OFF_H);
  bf16_t* qkv   = (bf16_t*)(ws + OFF_QKV);
  bf16_t* vT    = (bf16_t*)(ws + OFF_VT);
  bf16_t* attn  = (bf16_t*)(ws + OFF_ATTN);
  float*  x1    = (float*)(ws + OFF_X1);
  float*  part  = (float*)(ws + OFF_PART);
  bf16_t* mlph  = (bf16_t*)(ws + OFF_MLPH);
  float* out = (float*)d_out;

  convert_pack<<<dim3(4096, 7, 1), 256, 0, stream>>>(Wq, Wk, Wv, Wo, W1, W2,
                                                     bq, bk, bv, wbf, bqkv);
  ada_mod<<<1536, 256, 0, stream>>>(cond, Wada, bada, mod);
  ln_modulate<<<4096, 256, 0, stream>>>(x, mod, h, 0);
  // qkv = h @ [Wq;Wk;Wv]^T + bias
  gemm_bt<0><<<dim3(24, 32, 1), 256, 0, stream>>>(
      h, 1024, 0, wbf, 1024, 0, qkv, 3072, 0, 4096, 3072, 1024,
      bqkv, 1.f);
  transpose_v<<<dim3(16, 64, 1), 256, 0, stream>>>(qkv, vT);
  flash_attn<<<dim3(16, 64, 1), 256, 0, stream>>>(qkv, vT, attn);

  // Wo split-K=2: part[z] = attn[:, z*512:] @ Wo[:, z*512:]^T
  gemm_bt<1><<<dim3(8, 32, 2), 256, 0, stream>>>(
      attn, 1024, 512, wbf + (size_t)3 * MEG, 1024, 512, part, 1024, 4194304,
      4096, 1024, 512, nullptr, 1.f);
  // x1 = x + alpha1*(sum part + bo); h = modulate(ln(x1), beta2, gama2)
  reduce_ln<<<4096, 256, 0, stream>>>(part, x, bo, mod, x1, h);

  // mlph = gelu(h @ W1^T + b1)
  gemm_bt<3><<<dim3(32, 32, 1), 256, 0, stream>>>(
      h, 1024, 0, wbf + (size_t)4 * MEG, 1024, 0, mlph, 4096, 0,
      4096, 4096, 1024, b1, 1.f);
  // W2 split-K=2
  gemm_bt<1><<<dim3(8, 32, 2), 256, 0, stream>>>(
      mlph, 4096, 2048, wbf + (size_t)8 * MEG, 4096, 2048, part, 1024, 4194304,
      4096, 1024, 2048, nullptr, 1.f);
  reduce_w2<<<4096, 256, 0, stream>>>(part, x1, b2, mod, out);
}

// Round 3
// 393.128 us; speedup vs baseline: 1.0398x; 1.0286x over previous
//
#include <hip/hip_runtime.h>
#include <cstdint>

typedef __bf16 bf16_t;
typedef __bf16 bf16x4 __attribute__((ext_vector_type(4)));
typedef __bf16 bf16x8 __attribute__((ext_vector_type(8)));
typedef float f32x4 __attribute__((ext_vector_type(4)));

#define B_ 4
#define S_ 1024
#define D_ 1024
#define HID_ 4096
#define MEG (1u << 20)

// ---------------- workspace layout (bytes) ----------------
static const size_t OFF_WBF  = 0;                 // 12M bf16 (Wq,Wk,Wv,Wo,W1,W2)
static const size_t OFF_BQKV = 25165824;          // 3072 f32
static const size_t OFF_MOD  = 25178112;          // 4*6144 f32
static const size_t OFF_H    = 25276416;          // 4096*1024 bf16
static const size_t OFF_QKV  = 33665024;          // 4096*3072 bf16
static const size_t OFF_VT   = 58830848;          // 4*16*64*1024 bf16
static const size_t OFF_ATTN = 67219456;          // 4096*1024 bf16
static const size_t OFF_X1   = 75608064;          // 4096*1024 f32
static const size_t OFF_PART = 92385280;          // 2 * 4096*1024 f32 (split-K partials)
static const size_t OFF_MLPH = 159494144;         // 4096*4096 bf16 = 32MB

// ---------------- async global->LDS (16B/lane) ----------------
__device__ __forceinline__ void async_copy16(const bf16_t* g, bf16_t* l) {
  __builtin_amdgcn_global_load_lds(
      (__attribute__((address_space(1))) void*)(g),
      (__attribute__((address_space(3))) void*)(l), 16, 0, 0);
}

// ---------------- weight convert + bias pack ----------------
__global__ __launch_bounds__(256) void convert_pack(
    const float* __restrict__ Wq, const float* __restrict__ Wk,
    const float* __restrict__ Wv, const float* __restrict__ Wo,
    const float* __restrict__ W1, const float* __restrict__ W2,
    const float* __restrict__ bq, const float* __restrict__ bk,
    const float* __restrict__ bv, bf16_t* __restrict__ wbf,
    float* __restrict__ bqkv) {
  const int y = blockIdx.y;
  if (y == 6) {
    int i = blockIdx.x * 256 + threadIdx.x;
    if (i < 3072)
      bqkv[i] = i < 1024 ? bq[i] : (i < 2048 ? bk[i - 1024] : bv[i - 2048]);
    return;
  }
  const float* src; bf16_t* dst; int n;
  switch (y) {
    case 0: src = Wq; dst = wbf;           n = MEG;     break;
    case 1: src = Wk; dst = wbf + MEG;     n = MEG;     break;
    case 2: src = Wv; dst = wbf + 2*MEG;   n = MEG;     break;
    case 3: src = Wo; dst = wbf + 3*MEG;   n = MEG;     break;
    case 4: src = W1; dst = wbf + 4*MEG;   n = 4*MEG;   break;
    default: src = W2; dst = wbf + 8*MEG;  n = 4*MEG;   break;
  }
  int idx = (blockIdx.x * 256 + threadIdx.x) * 4;
  if (idx < n) {
    float4 v = *(const float4*)(src + idx);
    bf16x4 pk;
    pk.x = (__bf16)v.x; pk.y = (__bf16)v.y; pk.z = (__bf16)v.z; pk.w = (__bf16)v.w;
    *(bf16x4*)(dst + idx) = pk;
  }
}

// ---------------- adaLN: one wave per output o, all 4 batches ----------------
__global__ __launch_bounds__(256) void ada_mod(
    const float* __restrict__ cond, const float* __restrict__ Wada,
    const float* __restrict__ bada, float* __restrict__ mod) {
  const int wave = threadIdx.x >> 6, lane = threadIdx.x & 63;
  const int o = blockIdx.x * 4 + wave;      // 0..6143
  const float* wr = Wada + (size_t)o * D_;
  float a0 = 0.f, a1 = 0.f, a2 = 0.f, a3 = 0.f;
#pragma unroll
  for (int l = 0; l < 16; l++) {
    int i = l * 64 + lane;
    float w = wr[i];
    float c0 = cond[i], c1 = cond[1024 + i], c2 = cond[2048 + i], c3 = cond[3072 + i];
    a0 += w * (c0 / (1.0f + __expf(-c0)));
    a1 += w * (c1 / (1.0f + __expf(-c1)));
    a2 += w * (c2 / (1.0f + __expf(-c2)));
    a3 += w * (c3 / (1.0f + __expf(-c3)));
  }
#pragma unroll
  for (int offs = 32; offs; offs >>= 1) {
    a0 += __shfl_xor(a0, offs);
    a1 += __shfl_xor(a1, offs);
    a2 += __shfl_xor(a2, offs);
    a3 += __shfl_xor(a3, offs);
  }
  if (lane == 0) {
    float bb = bada[o];
    mod[o]          = a0 + bb;
    mod[6144 + o]   = a1 + bb;
    mod[12288 + o]  = a2 + bb;
    mod[18432 + o]  = a3 + bb;
  }
}

// ---------------- LayerNorm + modulate -> bf16 ----------------
__global__ __launch_bounds__(256) void ln_modulate(
    const float* __restrict__ X, const float* __restrict__ mod,
    bf16_t* __restrict__ H, int goff) {
  const int row = blockIdx.x;
  const int b = row >> 10;
  const int t = threadIdx.x;
  const float* xr = X + (size_t)row * D_;
  float4 xv = *(const float4*)(xr + t * 4);
  float s = xv.x + xv.y + xv.z + xv.w;
  float q = xv.x*xv.x + xv.y*xv.y + xv.z*xv.z + xv.w*xv.w;
  const int wave = t >> 6, lane = t & 63;
#pragma unroll
  for (int offs = 32; offs; offs >>= 1) {
    s += __shfl_down(s, offs);
    q += __shfl_down(q, offs);
  }
  __shared__ float sb[4][2];
  if (lane == 0) { sb[wave][0] = s; sb[wave][1] = q; }
  __syncthreads();
  float st = sb[0][0] + sb[1][0] + sb[2][0] + sb[3][0];
  float qt = sb[0][1] + sb[1][1] + sb[2][1] + sb[3][1];
  float mu = st * (1.0f / D_);
  float var = qt * (1.0f / D_) - mu * mu;
  float rstd = rsqrtf(var + 1e-6f);
  const float* mb = mod + (size_t)b * 6144 + goff;
  const int c = t * 4;
  float4 gm = *(const float4*)(mb + c);
  float4 bt = *(const float4*)(mb + 1024 + c);
  bf16x4 pk;
  pk.x = (__bf16)((xv.x - mu) * rstd * (1.0f + bt.x) + gm.x);
  pk.y = (__bf16)((xv.y - mu) * rstd * (1.0f + bt.y) + gm.y);
  pk.z = (__bf16)((xv.z - mu) * rstd * (1.0f + bt.z) + gm.z);
  pk.w = (__bf16)((xv.w - mu) * rstd * (1.0f + bt.w) + gm.w);
  *(bf16x4*)(H + (size_t)row * D_ + c) = pk;
}

// ---------------- V transpose: vT[b,h,d,s] <- qkv[b,s, 2048+h*64+d] ----------------
__global__ __launch_bounds__(256) void transpose_v(
    const bf16_t* __restrict__ qkv, bf16_t* __restrict__ vT) {
  __shared__ bf16_t tile[64][65];
  const int bh = blockIdx.y;
  const int b = bh >> 4, hh = bh & 15;
  const int s0 = blockIdx.x * 64;
  const int t = threadIdx.x;
  const int tx = t & 63, ty = t >> 6;
  const bf16_t* src = qkv + (size_t)b * S_ * 3072 + 2048 + hh * 64;
  for (int r = ty; r < 64; r += 4)
    tile[r][tx] = src[(size_t)(s0 + r) * 3072 + tx];
  __syncthreads();
  bf16_t* dst = vT + (size_t)bh * 64 * 1024;
  for (int r = ty; r < 64; r += 4)
    dst[(size_t)r * 1024 + s0 + tx] = tile[tx][r];
}

// ---------------- flash attention (v4) ----------------
// QBLK=128, 512 threads (8 waves), each wave owns 16 q-rows; K/V LDS shared
// by all 8 waves (halves per-CU K/V traffic vs QBLK=64). KBLK=128 softmax
// granularity. K/V double-buffered, prefetch before compute, one
// vmcnt(0)+barrier per tile. Per-wave P buffer reused per 64-col half
// (P-write -> PV interleaved, same-wave DS ordering). Cross-lane SUM
// reduction deferred to kernel end (per-lane partials commute with
// defer-max rescale). LDS = 32K(K)+32K(V)+16K(P) = 80KB -> 2 blocks/CU
// = 16 waves/CU (4/SIMD). __launch_bounds__(512,4) pins VGPR<=128.
__global__ __launch_bounds__(512, 4) void flash_attn(
    const bf16_t* __restrict__ qkv, const bf16_t* __restrict__ vT,
    bf16_t* __restrict__ attn) {
  __shared__ __align__(16) bf16_t Ks[2][2][64 * 64];
  __shared__ __align__(16) bf16_t Vs[2][2][64 * 64];
  __shared__ __align__(16) bf16_t Ps[8][16 * 64];

  const int t = threadIdx.x;
  const int wave = t >> 6, lane = t & 63;
  const int lm = lane & 15, quad = lane >> 4;
  const int bh = blockIdx.y;
  const int b = bh >> 4, hh = bh & 15;
  const int s0 = blockIdx.x * 128;

  const bf16_t* qbase = qkv + (size_t)b * S_ * 3072 + hh * 64;
  const bf16_t* kbase = qbase + 1024;
  const bf16_t* vbase = vT + (size_t)bh * (64 * 1024);

  // staging geometry: 512 threads cover a 64x64 sub-tile in ONE issue.
  // thread t -> row t>>3, LDS slot (t&7); slot s of row r holds chunk s^(r&7)
  const int row0 = t >> 3;            // 0..63
  const int cg = (t & 7) ^ (row0 & 7);
  const int od = t * 8;               // LDS element offset

  // prologue: Q(128 rows) -> Ks[1][0..1] (temp), K tile0 -> Ks[0][0..1],
  // V tile0 -> Vs[0][0..1]
  async_copy16(qbase + (size_t)(s0 + row0) * 3072 + cg * 8, &Ks[1][0][od]);
  async_copy16(qbase + (size_t)(s0 + 64 + row0) * 3072 + cg * 8, &Ks[1][1][od]);
  async_copy16(kbase + (size_t)row0 * 3072 + cg * 8, &Ks[0][0][od]);
  async_copy16(kbase + (size_t)(64 + row0) * 3072 + cg * 8, &Ks[0][1][od]);
  async_copy16(vbase + (size_t)row0 * 1024 + cg * 8, &Vs[0][0][od]);
  async_copy16(vbase + (size_t)row0 * 1024 + 64 + cg * 8, &Vs[0][1][od]);
  __syncthreads();

  // Q fragments to registers: row = wave*16+lm in [0,128)
  bf16x8 aq0, aq1;
  {
    const int rq = wave * 16 + lm;
    const int qh = rq >> 6, qr = rq & 63;
    const int rbq = lm & 7;             // qr & 7 == rq & 7 == lm & 7
    aq0 = *(const bf16x8*)&Ks[1][qh][qr * 64 + (quad ^ rbq) * 8];
    aq1 = *(const bf16x8*)&Ks[1][qh][qr * 64 + ((4 + quad) ^ rbq) * 8];
  }
  __syncthreads();   // all waves done reading Q; Ks[1] reusable for tile 1

  f32x4 accO[4] = {};
  float mrow[4], lsum[4];
#pragma unroll
  for (int r = 0; r < 4; r++) { mrow[r] = -1e30f; lsum[r] = 0.f; }

  const float SC = 0.18033688f;         // 0.125 * log2(e): exp2 domain
  const int rb = lm & 7;
  bf16_t* Pw = Ps[wave];

  for (int tt = 0; tt < 8; ++tt) {
    const int cur = tt & 1;
    // prefetch next 128-wide K/V tile while this one computes
    if (tt < 7) {
      const int nb = cur ^ 1;
      const size_t k0n = (size_t)(tt + 1) << 7;
      async_copy16(kbase + (k0n + row0) * 3072 + cg * 8, &Ks[nb][0][od]);
      async_copy16(kbase + (k0n + 64 + row0) * 3072 + cg * 8, &Ks[nb][1][od]);
      async_copy16(vbase + (size_t)row0 * 1024 + k0n + cg * 8, &Vs[nb][0][od]);
      async_copy16(vbase + (size_t)row0 * 1024 + k0n + 64 + cg * 8, &Vs[nb][1][od]);
    }

    // QK^T: accS[h*4+ni] holds S[q=quad*4+r][k = h*64 + ni*16 + lm]
    f32x4 accS[8];
#pragma unroll
    for (int j = 0; j < 8; j++) accS[j] = (f32x4){0.f, 0.f, 0.f, 0.f};
    __builtin_amdgcn_s_setprio(1);
#pragma unroll
    for (int hf = 0; hf < 2; hf++) {
#pragma unroll
      for (int ni = 0; ni < 4; ni++) {
        const int rk = ni * 16 + lm;
        bf16x8 b0 = *(const bf16x8*)&Ks[cur][hf][rk * 64 + ((quad ^ rb)) * 8];
        bf16x8 b1 = *(const bf16x8*)&Ks[cur][hf][rk * 64 + (((4 + quad) ^ rb)) * 8];
        f32x4 a = accS[hf * 4 + ni];
        a = __builtin_amdgcn_mfma_f32_16x16x32_bf16(aq0, b0, a, 0, 0, 0);
        a = __builtin_amdgcn_mfma_f32_16x16x32_bf16(aq1, b1, a, 0, 0, 0);
        accS[hf * 4 + ni] = a;
      }
    }
    __builtin_amdgcn_s_setprio(0);

    // row max (cross-lane within quad) + T13 defer-max (THR=8, exp2 domain)
    float mx[4];
#pragma unroll
    for (int r = 0; r < 4; r++) {
      float m0 = fmaxf(fmaxf(accS[0][r], accS[1][r]), fmaxf(accS[2][r], accS[3][r]));
      float m1 = fmaxf(fmaxf(accS[4][r], accS[5][r]), fmaxf(accS[6][r], accS[7][r]));
      float m8 = fmaxf(m0, m1);
      m8 = fmaxf(m8, __shfl_xor(m8, 1));
      m8 = fmaxf(m8, __shfl_xor(m8, 2));
      m8 = fmaxf(m8, __shfl_xor(m8, 4));
      m8 = fmaxf(m8, __shfl_xor(m8, 8));
      mx[r] = m8 * SC;
    }
    bool ok = (mx[0] - mrow[0] <= 8.0f) && (mx[1] - mrow[1] <= 8.0f) &&
              (mx[2] - mrow[2] <= 8.0f) && (mx[3] - mrow[3] <= 8.0f);
    if (!__all(ok)) {
#pragma unroll
      for (int r = 0; r < 4; r++) {
        float mnew = fmaxf(mrow[r], mx[r]);
        float al = exp2f(mrow[r] - mnew);
        mrow[r] = mnew;
        lsum[r] *= al;
#pragma unroll
        for (int di = 0; di < 4; di++) accO[di][r] *= al;
      }
    }
    // exp2 + per-lane partial sum (cross-lane reduce deferred to end)
#pragma unroll
    for (int r = 0; r < 4; r++) {
      float sum = 0.f;
#pragma unroll
      for (int j = 0; j < 8; j++) {
        float p = exp2f(accS[j][r] * SC - mrow[r]);
        accS[j][r] = p;
        sum += p;
      }
      lsum[r] += sum;
    }

    // per 64-col half: P -> LDS (swizzled), then PV (same-wave DS ordering)
#pragma unroll
    for (int hf = 0; hf < 2; hf++) {
#pragma unroll
      for (int jj = 0; jj < 4; jj++)
#pragma unroll
        for (int r = 0; r < 4; r++) {
          int prow = quad * 4 + r;
          int c = jj * 16 + lm;
          Pw[prow * 64 + (((c >> 3) ^ (prow & 7)) << 3) + (c & 7)] =
              (__bf16)accS[hf * 4 + jj][r];
        }
      __builtin_amdgcn_s_setprio(1);
#pragma unroll
      for (int loc = 0; loc < 2; loc++) {
        bf16x8 ap = *(const bf16x8*)&Pw[lm * 64 + (((loc * 4 + quad) ^ rb)) * 8];
#pragma unroll
        for (int di = 0; di < 4; di++) {
          const int rv = di * 16 + lm;
          bf16x8 vv = *(const bf16x8*)&Vs[cur][hf]
              [rv * 64 + (((loc * 4 + quad) ^ rb)) * 8];
          accO[di] = __builtin_amdgcn_mfma_f32_16x16x32_bf16(ap, vv, accO[di], 0, 0, 0);
        }
      }
      __builtin_amdgcn_s_setprio(0);
    }
    __syncthreads();   // drains prefetch (vmcnt) + guards buffer swap
  }

  // deferred cross-lane sum reduce (within quad: xor 1,2,4,8)
#pragma unroll
  for (int r = 0; r < 4; r++) {
    float sv = lsum[r];
    sv += __shfl_xor(sv, 1);
    sv += __shfl_xor(sv, 2);
    sv += __shfl_xor(sv, 4);
    sv += __shfl_xor(sv, 8);
    lsum[r] = sv;
  }

  // epilogue: normalize, stage O in Pw (same swizzle), vectorized store
#pragma unroll
  for (int r = 0; r < 4; r++) {
    float inv = 1.0f / lsum[r];
    int prow = quad * 4 + r;
#pragma unroll
    for (int di = 0; di < 4; di++) {
      int col = di * 16 + lm;
      int cph = (col >> 3) ^ (prow & 7);
      Pw[prow * 64 + cph * 8 + (col & 7)] = (__bf16)(accO[di][r] * inv);
    }
  }
  bf16_t* abase = attn + (size_t)b * S_ * 1024 +
                  (size_t)(s0 + wave * 16) * 1024 + hh * 64;
#pragma unroll
  for (int it = 0; it < 2; it++) {
    int slot = it * 64 + lane;
    int orow = slot >> 3;
    int gc = slot & 7;
    int cph = gc ^ (orow & 7);
    bf16x8 val = *(const bf16x8*)&Pw[orow * 64 + cph * 8];
    *(bf16x8*)(abase + (size_t)orow * 1024 + gc * 8) = val;
  }
}

// ---------------- generic C = A * B^T GEMM, pipelined double-buffer ----------------
// BK=32, 2 LDS buffers, one barrier per K-iter, loads issued after the barrier.
// LDS slot swizzle: slot s of row r holds global chunk s ^ ((r>>1)&3)
// (reader granule = 4*(lm&1) + quad^((lm>>1)&3): all 8 granules x2 -> conflict-free).
// XCD-aware block swizzle (requires gridDim.y == 32): per-XCD 8x4 patches.
// M,N multiples of 128; K multiple of 32.
// EPI: 0 = (+bias) -> bf16 ; 1 = *scale -> f32 ; 3 = gelu_tanh(acc+bias) -> bf16
template <int EPI>
__global__ __launch_bounds__(256) void gemm_bt(
    const bf16_t* __restrict__ A, int lda, long long sAz,
    const bf16_t* __restrict__ B, int ldb, long long sBz,
    void* __restrict__ Cv, int ldc, long long sCz,
    int M, int N, int K,
    const float* __restrict__ bias,
    float scale) {
  __shared__ __align__(16) bf16_t As[2][128 * 32];
  __shared__ __align__(16) bf16_t Bs[2][128 * 32];

  const int z = blockIdx.z;
  A += (size_t)z * sAz;
  B += (size_t)z * sBz;

  // XCD-aware swizzle: dispatch id d -> XCD d&7; give each XCD an 8x4 tile patch
  {
    int d = blockIdx.x + gridDim.x * blockIdx.y;
    int xcd = d & 7, sId = d >> 3;
    int qq = sId & 31, panel = sId >> 5;
    const int bx = panel * 8 + (qq >> 2);
    const int by = xcd * 4 + (qq & 3);
    // fallthrough uses m0/n0 below
    const int t = threadIdx.x;
    const int wave = t >> 6;
    const int lane = t & 63;
    const int lm = lane & 15;
    const int quad = lane >> 4;
    const int wr = wave >> 1;
    const int wc = wave & 1;

    const int m0 = by * 128;
    const int n0 = bx * 128;

    f32x4 acc[4][4] = {};

    // staging: thread t covers rows {t>>2, 64+(t>>2)}, LDS slot t&3 holds
    // global chunk (t&3) ^ ((srow>>1)&3)  [same for srow and srow+64]
    const int srow = t >> 2;
    const int gch = (t & 3) ^ ((srow >> 1) & 3);
    const int lds_off = t * 8;
    const bf16_t* Ap0 = A + (size_t)(m0 + srow) * lda + gch * 8;
    const bf16_t* Ap1 = A + (size_t)(m0 + 64 + srow) * lda + gch * 8;
    const bf16_t* Bp0 = B + (size_t)(n0 + srow) * ldb + gch * 8;
    const bf16_t* Bp1 = B + (size_t)(n0 + 64 + srow) * ldb + gch * 8;

    // reader slot offset: loop-invariant ((ra>>1)&3 == (lm>>1)&3)
    const int sOff = (quad ^ ((lm >> 1) & 3)) * 8;

    const int niter = K >> 5;
    async_copy16(Ap0, &As[0][lds_off]);
    async_copy16(Ap1, &As[0][2048 + lds_off]);
    async_copy16(Bp0, &Bs[0][lds_off]);
    async_copy16(Bp1, &Bs[0][2048 + lds_off]);

    for (int it = 0; it < niter; ++it) {
      asm volatile("s_waitcnt vmcnt(0)\n\ts_barrier" ::: "memory");
      if (it + 1 < niter) {
        const int ko = (it + 1) << 5;
        const int nb = (it + 1) & 1;
        async_copy16(Ap0 + ko, &As[nb][lds_off]);
        async_copy16(Ap1 + ko, &As[nb][2048 + lds_off]);
        async_copy16(Bp0 + ko, &Bs[nb][lds_off]);
        async_copy16(Bp1 + ko, &Bs[nb][2048 + lds_off]);
      }
      const int cb = it & 1;
      bf16x8 af[4], bfr[4];
#pragma unroll
      for (int i = 0; i < 4; i++) {
        af[i] = *(const bf16x8*)&As[cb][(wr * 64 + i * 16 + lm) * 32 + sOff];
        bfr[i] = *(const bf16x8*)&Bs[cb][(wc * 64 + i * 16 + lm) * 32 + sOff];
      }
#pragma unroll
      for (int mi = 0; mi < 4; mi++)
#pragma unroll
        for (int ni = 0; ni < 4; ni++)
          acc[mi][ni] = __builtin_amdgcn_mfma_f32_16x16x32_bf16(
              af[mi], bfr[ni], acc[mi][ni], 0, 0, 0);
    }

    const size_t cz = (size_t)z * sCz;
#pragma unroll
    for (int mi = 0; mi < 4; mi++) {
#pragma unroll
      for (int ni = 0; ni < 4; ni++) {
#pragma unroll
        for (int r = 0; r < 4; r++) {
          int row = m0 + wr * 64 + mi * 16 + quad * 4 + r;
          int col = n0 + wc * 64 + ni * 16 + lm;
          float v = acc[mi][ni][r];
          size_t idx = cz + (size_t)row * ldc + col;
          if (EPI == 1) {
            ((float*)Cv)[idx] = v * scale;
          } else if (EPI == 0) {
            if (bias) v += bias[col];
            ((bf16_t*)Cv)[idx] = (__bf16)v;
          } else if (EPI == 3) {
            v += bias[col];
            float u = 1.5957691216f * (v + 0.044715f * v * v * v);
            float g = v / (1.0f + __expf(-u));
            ((bf16_t*)Cv)[idx] = (__bf16)g;
          }
        }
      }
    }
  }
}

// ---------------- Wo split-K reduce + residual + LN2 + modulate ----------------
__global__ __launch_bounds__(256) void reduce_ln(
    const float* __restrict__ part, const float* __restrict__ x,
    const float* __restrict__ bo, const float* __restrict__ mod,
    float* __restrict__ x1, bf16_t* __restrict__ h) {
  const int row = blockIdx.x;
  const int b = row >> 10;
  const int t = threadIdx.x;
  const int c = t * 4;
  const size_t idx = (size_t)row * 1024 + c;
  float4 p0 = *(const float4*)(part + idx);
  float4 p1 = *(const float4*)(part + 4194304 + idx);
  float4 bb = *(const float4*)(bo + c);
  float4 al = *(const float4*)(mod + (size_t)b * 6144 + 2048 + c);
  float4 xs = *(const float4*)(x + idx);
  float4 xv;
  xv.x = xs.x + al.x * (p0.x + p1.x + bb.x);
  xv.y = xs.y + al.y * (p0.y + p1.y + bb.y);
  xv.z = xs.z + al.z * (p0.z + p1.z + bb.z);
  xv.w = xs.w + al.w * (p0.w + p1.w + bb.w);
  *(float4*)(x1 + idx) = xv;

  float s = xv.x + xv.y + xv.z + xv.w;
  float q = xv.x*xv.x + xv.y*xv.y + xv.z*xv.z + xv.w*xv.w;
  const int wave = t >> 6, lane = t & 63;
#pragma unroll
  for (int offs = 32; offs; offs >>= 1) {
    s += __shfl_down(s, offs);
    q += __shfl_down(q, offs);
  }
  __shared__ float sb[4][2];
  if (lane == 0) { sb[wave][0] = s; sb[wave][1] = q; }
  __syncthreads();
  float st = sb[0][0] + sb[1][0] + sb[2][0] + sb[3][0];
  float qt = sb[0][1] + sb[1][1] + sb[2][1] + sb[3][1];
  float mu = st * (1.0f / D_);
  float var = qt * (1.0f / D_) - mu * mu;
  float rstd = rsqrtf(var + 1e-6f);
  const float* mb = mod + (size_t)b * 6144 + 3072;
  float4 gm = *(const float4*)(mb + c);
  float4 bt = *(const float4*)(mb + 1024 + c);
  bf16x4 pk;
  pk.x = (__bf16)((xv.x - mu) * rstd * (1.0f + bt.x) + gm.x);
  pk.y = (__bf16)((xv.y - mu) * rstd * (1.0f + bt.y) + gm.y);
  pk.z = (__bf16)((xv.z - mu) * rstd * (1.0f + bt.z) + gm.z);
  pk.w = (__bf16)((xv.w - mu) * rstd * (1.0f + bt.w) + gm.w);
  *(bf16x4*)(h + idx) = pk;
}

// ---------------- W2 split-K(2) reduction + epilogue ----------------
__global__ __launch_bounds__(256) void reduce_w2(
    const float* __restrict__ part, const float* __restrict__ x1,
    const float* __restrict__ b2, const float* __restrict__ mod,
    float* __restrict__ out) {
  const int idx = (blockIdx.x * 256 + threadIdx.x) * 4;
  const int col = idx & 1023;
  const int row = idx >> 10;
  const int b = row >> 10;
  float4 s0 = *(const float4*)(part + idx);
  float4 s1 = *(const float4*)(part + 4194304 + idx);
  float4 bb = *(const float4*)(b2 + col);
  float4 al = *(const float4*)(mod + (size_t)b * 6144 + 5120 + col);
  float4 rs = *(const float4*)(x1 + idx);
  float4 o;
  o.x = rs.x + al.x * (s0.x + s1.x + bb.x);
  o.y = rs.y + al.y * (s0.y + s1.y + bb.y);
  o.z = rs.z + al.z * (s0.z + s1.z + bb.z);
  o.w = rs.w + al.w * (s0.w + s1.w + bb.w);
  *(float4*)(out + idx) = o;
}

extern "C" void kernel_launch(void* const* d_in, const int* in_sizes, int n_in,
                              void* d_out, int out_size, void* d_ws, size_t ws_size,
                              hipStream_t stream) {
  (void)in_sizes; (void)n_in; (void)out_size; (void)ws_size;
  const float* x    = (const float*)d_in[0];
  const float* cond = (const float*)d_in[1];
  const float* Wq   = (const float*)d_in[2];
  const float* bq   = (const float*)d_in[3];
  const float* Wk   = (const float*)d_in[4];
  const float* bk   = (const float*)d_in[5];
  const float* Wv   = (const float*)d_in[6];
  const float* bv   = (const float*)d_in[7];
  const float* Wo   = (const float*)d_in[8];
  const float* bo   = (const float*)d_in[9];
  const float* W1   = (const float*)d_in[10];
  const float* b1   = (const float*)d_in[11];
  const float* W2   = (const float*)d_in[12];
  const float* b2   = (const float*)d_in[13];
  const float* Wada = (const float*)d_in[14];
  const float* bada = (const float*)d_in[15];

  uint8_t* ws = (uint8_t*)d_ws;
  bf16_t* wbf   = (bf16_t*)(ws + OFF_WBF);
  float*  bqkv  = (float*)(ws + OFF_BQKV);
  float*  mod   = (float*)(ws + OFF_MOD);
  bf16_t* h     = (bf16_t*)(ws + OFF_H);
  bf16_t* qkv   = (bf16_t*)(ws + OFF_QKV);
  bf16_t* vT    = (bf16_t*)(ws + OFF_VT);
  bf16_t* attn  = (bf16_t*)(ws + OFF_ATTN);
  float*  x1    = (float*)(ws + OFF_X1);
  float*  part  = (float*)(ws + OFF_PART);
  bf16_t* mlph  = (bf16_t*)(ws + OFF_MLPH);
  float* out = (float*)d_out;

  convert_pack<<<dim3(4096, 7, 1), 256, 0, stream>>>(Wq, Wk, Wv, Wo, W1, W2,
                                                     bq, bk, bv, wbf, bqkv);
  ada_mod<<<1536, 256, 0, stream>>>(cond, Wada, bada, mod);
  ln_modulate<<<4096, 256, 0, stream>>>(x, mod, h, 0);
  // qkv = h @ [Wq;Wk;Wv]^T + bias
  gemm_bt<0><<<dim3(24, 32, 1), 256, 0, stream>>>(
      h, 1024, 0, wbf, 1024, 0, qkv, 3072, 0, 4096, 3072, 1024,
      bqkv, 1.f);
  transpose_v<<<dim3(16, 64, 1), 256, 0, stream>>>(qkv, vT);
  flash_attn<<<dim3(8, 64, 1), 512, 0, stream>>>(qkv, vT, attn);

  // Wo split-K=2: part[z] = attn[:, z*512:] @ Wo[:, z*512:]^T
  gemm_bt<1><<<dim3(8, 32, 2), 256, 0, stream>>>(
      attn, 1024, 512, wbf + (size_t)3 * MEG, 1024, 512, part, 1024, 4194304,
      4096, 1024, 512, nullptr, 1.f);
  // x1 = x + alpha1*(sum part + bo); h = modulate(ln(x1), beta2, gama2)
  reduce_ln<<<4096, 256, 0, stream>>>(part, x, bo, mod, x1, h);

  // mlph = gelu(h @ W1^T + b1)
  gemm_bt<3><<<dim3(32, 32, 1), 256, 0, stream>>>(
      h, 1024, 0, wbf + (size_t)4 * MEG, 1024, 0, mlph, 4096, 0,
      4096, 4096, 1024, b1, 1.f);
  // W2 split-K=2
  gemm_bt<1><<<dim3(8, 32, 2), 256, 0, stream>>>(
      mlph, 4096, 2048, wbf + (size_t)8 * MEG, 4096, 2048, part, 1024, 4194304,
      4096, 1024, 2048, nullptr, 1.f);
  reduce_w2<<<4096, 256, 0, stream>>>(part, x1, b2, mod, out);
}